// Round 3
// baseline (211.053 us; speedup 1.0000x reference)
//
#include <hip/hip_runtime.h>
#include <math.h>

#define NW     10
#define DIM    1024
#define QDEPTH 16

typedef __attribute__((ext_vector_type(8))) _Float16 f16x8;
typedef __attribute__((ext_vector_type(4))) _Float16 f16x4;
typedef __attribute__((ext_vector_type(4))) float    f32x4;

// ---------------- ws layout ----------------
// gates : @0        (160 gates * 8 floats = 5120 B)
// hperm : @8192     (16*1024*4 = 64 KB)  inverse CNOT-block permutations
// invs  : @81920    (8192*4 = 32 KB)
// Xh    : @1 MB     (8192*1024*2 = 16 MB)   f16 cast of x, row-major (B,K)
// B_il  : @18 MB    (2048*1024*2 = 4 MB)    f16, rows 2j=Re U[j,:], 2j+1=Im U[j,:]
#define WS_GATES 0
#define WS_HPERM 8192
#define WS_INVS  81920
#define WS_XH    (1u << 20)
#define WS_BIL   (18u << 20)

__global__ __launch_bounds__(1024)
void prep_kernel(const float* __restrict__ w, float* __restrict__ gates,
                 int* __restrict__ hperm) {
    int t = threadIdx.x;
    const float PI = 3.14159265358979323846f;
    if (t < QDEPTH * NW) {
        // Rot(phi,theta,omega) = RZ(omega) RY(theta) RZ(phi); angles = tanh(w)*pi
        float phi   = tanhf(w[t*3 + 0]) * PI;
        float theta = tanhf(w[t*3 + 1]) * PI;
        float omega = tanhf(w[t*3 + 2]) * PI;
        float ch = cosf(theta * 0.5f), sh = sinf(theta * 0.5f);
        float ap = (phi + omega) * 0.5f;
        float am = (phi - omega) * 0.5f;
        float* g = gates + t * 8;
        g[0] =  cosf(ap) * ch;  g[1] = -sinf(ap) * ch;   // m00
        g[2] = -cosf(am) * sh;  g[3] = -sinf(am) * sh;   // m01
        g[4] =  cosf(am) * sh;  g[5] = -sinf(am) * sh;   // m10
        g[6] =  cosf(ap) * ch;  g[7] =  sinf(ap) * ch;   // m11
    }
    // Forward CNOT-block gather G_l (verified in round 1): state'[v] = state[G_l(v)].
    // We need the transpose P_l^T, which gathers with H_l = G_l^{-1}:
    // scatter-invert: H_l[G_l(v)] = v.
    int v = t;
    for (int l = 0; l < QDEPTH; ++l) {
        int r = (l % (NW - 1)) + 1;
        int u = v;
        for (int wq = NW - 1; wq >= 0; --wq) {
            int bc = 9 - wq;
            int bt = 9 - ((wq + r) % NW);
            u ^= ((u >> bc) & 1) << bt;
        }
        hperm[l * DIM + u] = v;
    }
}

// Row-of-U builder: wave j computes U^T e_j (= row j of U) entirely in registers.
// U^T = M_0^T ... M_15^T applied rightmost-first: for l=15..0 apply P_l^T
// (gather H_l via wave-private LDS) then R_l^T (transposed Rot gates:
// bits 6..9 in-register pairs, bits 0..5 via __shfl_xor).
__global__ __launch_bounds__(256)
void ubuildT_kernel(const float* __restrict__ gates, const int* __restrict__ hperm,
                    _Float16* __restrict__ Bil) {
    __shared__ float2 stg[4][DIM];   // one 8KB region per wave
    const int t    = threadIdx.x;
    const int lane = t & 63;
    const int wid  = t >> 6;
    const int j    = blockIdx.x * 4 + wid;      // row index of U
    float2* my = stg[wid];

    float re[16], im[16];
    const int rj = j >> 6, lj = j & 63;
    #pragma unroll
    for (int r = 0; r < 16; ++r) {               // st = e_j (compile-time reg index)
        re[r] = (r == rj && lane == lj) ? 1.0f : 0.0f;
        im[r] = 0.0f;
    }

    for (int l = QDEPTH - 1; l >= 0; --l) {
        // ---- P_l^T: st'[v] = st[H_l(v)], via wave-private LDS ----
        #pragma unroll
        for (int r = 0; r < 16; ++r)
            my[(r << 6) | lane] = make_float2(re[r], im[r]);
        const int* hl = hperm + l * DIM;
        int idx[16];
        #pragma unroll
        for (int r = 0; r < 16; ++r)
            idx[r] = hl[(r << 6) | lane];
        #pragma unroll
        for (int r = 0; r < 16; ++r) {
            float2 a = my[idx[r]];
            re[r] = a.x; im[r] = a.y;
        }

        const float* gl = gates + l * NW * 8;

        // ---- R_l^T, bits 6..9 (wires 3..0): register pairs ----
        #pragma unroll
        for (int bb = 6; bb <= 9; ++bb) {
            const float* g = gl + (9 - bb) * 8;
            // transposed gate: T00=m00, T01=m10, T10=m01, T11=m11
            float T00r = g[0], T00i = g[1];
            float T01r = g[4], T01i = g[5];
            float T10r = g[2], T10i = g[3];
            float T11r = g[6], T11i = g[7];
            const int m = 1 << (bb - 6);
            #pragma unroll
            for (int r = 0; r < 16; ++r) {
                if (!(r & m)) {
                    const int r1 = r | m;
                    float p0r = re[r],  p0i = im[r];
                    float p1r = re[r1], p1i = im[r1];
                    re[r]  = T00r*p0r - T00i*p0i + T01r*p1r - T01i*p1i;
                    im[r]  = T00r*p0i + T00i*p0r + T01r*p1i + T01i*p1r;
                    re[r1] = T10r*p0r - T10i*p0i + T11r*p1r - T11i*p1i;
                    im[r1] = T10r*p0i + T10i*p0r + T11r*p1i + T11i*p1r;
                }
            }
        }

        // ---- R_l^T, bits 0..5 (wires 9..4): cross-lane via shfl_xor ----
        #pragma unroll
        for (int bb = 0; bb <= 5; ++bb) {
            const float* g = gl + (9 - bb) * 8;
            float T00r = g[0], T00i = g[1];
            float T01r = g[4], T01i = g[5];
            float T10r = g[2], T10i = g[3];
            float T11r = g[6], T11i = g[7];
            const int mask = 1 << bb;
            const bool hi = (lane >> bb) & 1;
            // lane with bit=0 holds p0: new = T00*own + T01*other
            // lane with bit=1 holds p1: new = T11*own + T10*other
            const float cor = hi ? T11r : T00r;
            const float coi = hi ? T11i : T00i;
            const float cxr = hi ? T10r : T01r;
            const float cxi = hi ? T10i : T01i;
            #pragma unroll
            for (int r = 0; r < 16; ++r) {
                float orr = __shfl_xor(re[r], mask, 64);
                float oii = __shfl_xor(im[r], mask, 64);
                float nr = cor*re[r] - coi*im[r] + cxr*orr - cxi*oii;
                float ni = cor*im[r] + coi*re[r] + cxr*oii + cxi*orr;
                re[r] = nr; im[r] = ni;
            }
        }
    }

    // ---- write row j: Bil[2j][k]=Re U[j,k], Bil[2j+1][k]=Im U[j,k] ----
    _Float16* row0 = Bil + (size_t)(2 * j) * DIM;
    _Float16* row1 = row0 + DIM;
    #pragma unroll
    for (int r = 0; r < 16; ++r) {
        const int k = (r << 6) | lane;
        row0[k] = (_Float16)re[r];
        row1[k] = (_Float16)im[r];
    }
}

// Per-row sumsq + f16 cast. One wave per batch row.
__global__ __launch_bounds__(64)
void normcast_kernel(const float* __restrict__ x, _Float16* __restrict__ Xh,
                     float* __restrict__ invs) {
    const int b = blockIdx.x;
    const int l = threadIdx.x;
    const float4* xr = (const float4*)(x + (size_t)b * DIM);
    float4 v[4];
    float ss = 0.f;
    #pragma unroll
    for (int c = 0; c < 4; ++c) {
        v[c] = xr[l + c * 64];
        ss += v[c].x*v[c].x + v[c].y*v[c].y + v[c].z*v[c].z + v[c].w*v[c].w;
    }
    #pragma unroll
    for (int o = 32; o >= 1; o >>= 1) ss += __shfl_down(ss, o, 64);
    ss = __shfl(ss, 0, 64);
    if (l == 0) invs[b] = 1024.0f / ss;
    f16x4* xo = (f16x4*)(Xh + (size_t)b * DIM);
    #pragma unroll
    for (int c = 0; c < 4; ++c) {
        f16x4 h;
        h[0] = (_Float16)v[c].x; h[1] = (_Float16)v[c].y;
        h[2] = (_Float16)v[c].z; h[3] = (_Float16)v[c].w;
        xo[l + c * 64] = h;
    }
}

// C[b,n] = sum_k Xh[b,k] * Bil[n,k];  out[b, n>>1] = clip(invs[b]*(c_even^2+c_odd^2), 0, 1)
// M=8192, N=2048, K=1024. 128x128 tile, BK=32, 4 waves (2x2), 4x4 16x16x32 frags/wave.
#define BM 128
#define BN 128
#define BK 32

__global__ __launch_bounds__(256)
void gemm_kernel(const _Float16* __restrict__ A, const _Float16* __restrict__ B,
                 const float* __restrict__ invs, float* __restrict__ out) {
    __shared__ _Float16 As[BM * BK];   // 8 KB, row-major [128][32]
    __shared__ _Float16 Bs[BN * BK];   // 8 KB
    const int t    = threadIdx.x;
    const int lane = t & 63;
    const int wid  = t >> 6;
    const int wm = wid >> 1, wn = wid & 1;
    const int m0 = blockIdx.y * BM;
    const int n0 = blockIdx.x * BN;

    const int srow   = t >> 2;
    const int schunk = (t & 3) * 8;
    const _Float16* Ag = A + (size_t)(m0 + srow) * 1024 + schunk;
    const _Float16* Bg = B + (size_t)(n0 + srow) * 1024 + schunk;

    f32x4 acc[4][4];
    const f32x4 zero = {0.f, 0.f, 0.f, 0.f};
    #pragma unroll
    for (int i = 0; i < 4; ++i)
        #pragma unroll
        for (int j = 0; j < 4; ++j) acc[i][j] = zero;

    const int fr = lane & 15;
    const int fk = (lane >> 4) * 8;

    for (int kt = 0; kt < 1024; kt += BK) {
        __syncthreads();
        __builtin_amdgcn_global_load_lds(
            (const __attribute__((address_space(1))) void*)(Ag + kt),
            (__attribute__((address_space(3))) void*)(As + t * 8), 16, 0, 0);
        __builtin_amdgcn_global_load_lds(
            (const __attribute__((address_space(1))) void*)(Ag + kt + 64 * 1024),
            (__attribute__((address_space(3))) void*)(As + 2048 + t * 8), 16, 0, 0);
        __builtin_amdgcn_global_load_lds(
            (const __attribute__((address_space(1))) void*)(Bg + kt),
            (__attribute__((address_space(3))) void*)(Bs + t * 8), 16, 0, 0);
        __builtin_amdgcn_global_load_lds(
            (const __attribute__((address_space(1))) void*)(Bg + kt + 64 * 1024),
            (__attribute__((address_space(3))) void*)(Bs + 2048 + t * 8), 16, 0, 0);
        __syncthreads();

        f16x8 af[4], bf[4];
        #pragma unroll
        for (int mf = 0; mf < 4; ++mf)
            af[mf] = *(const f16x8*)(As + (wm * 64 + mf * 16 + fr) * BK + fk);
        #pragma unroll
        for (int nf = 0; nf < 4; ++nf)
            bf[nf] = *(const f16x8*)(Bs + (wn * 64 + nf * 16 + fr) * BK + fk);
        #pragma unroll
        for (int mf = 0; mf < 4; ++mf)
            #pragma unroll
            for (int nf = 0; nf < 4; ++nf)
                acc[mf][nf] = __builtin_amdgcn_mfma_f32_16x16x32_f16(
                    af[mf], bf[nf], acc[mf][nf], 0, 0, 0);
    }

    const int colf = lane & 15;
    const int rowf = (lane >> 4) * 4;
    #pragma unroll
    for (int mf = 0; mf < 4; ++mf) {
        #pragma unroll
        for (int nf = 0; nf < 4; ++nf) {
            const int n = n0 + wn * 64 + nf * 16 + colf;
            #pragma unroll
            for (int r = 0; r < 4; ++r) {
                const int row = m0 + wm * 64 + mf * 16 + rowf + r;
                float vv = acc[mf][nf][r];
                float sq = vv * vv;
                float other = __shfl_xor(sq, 1, 64);
                if (!(lane & 1)) {
                    float p = fminf((sq + other) * invs[row], 1.0f);
                    out[(size_t)row * DIM + (n >> 1)] = p;
                }
            }
        }
    }
}

extern "C" void kernel_launch(void* const* d_in, const int* in_sizes, int n_in,
                              void* d_out, int out_size, void* d_ws, size_t ws_size,
                              hipStream_t stream) {
    const float* x = (const float*)d_in[0];     // (8192,1,32,32) fp32
    const float* w = (const float*)d_in[1];     // (16,10,3) fp32
    float* out = (float*)d_out;                 // (8192,1,32,32) fp32

    char* ws = (char*)d_ws;
    float*     gates = (float*)(ws + WS_GATES);
    int*       hperm = (int*)(ws + WS_HPERM);
    float*     invs  = (float*)(ws + WS_INVS);
    _Float16*  Xh    = (_Float16*)(ws + WS_XH);
    _Float16*  Bil   = (_Float16*)(ws + WS_BIL);

    prep_kernel<<<1, 1024, 0, stream>>>(w, gates, hperm);
    normcast_kernel<<<8192, 64, 0, stream>>>(x, Xh, invs);
    ubuildT_kernel<<<256, 256, 0, stream>>>(gates, hperm, Bil);
    gemm_kernel<<<dim3(16, 64), 256, 0, stream>>>(Xh, Bil, invs, out);
}

// Round 4
// 158.179 us; speedup vs baseline: 1.3343x; 1.3343x over previous
//
#include <hip/hip_runtime.h>
#include <math.h>

#define NW     10
#define DIM    1024
#define QDEPTH 16

typedef __attribute__((ext_vector_type(8))) _Float16 f16x8;
typedef __attribute__((ext_vector_type(4))) _Float16 f16x4;
typedef __attribute__((ext_vector_type(2))) _Float16 f16x2;
typedef __attribute__((ext_vector_type(4))) float    f32x4;

// ---------------- ws layout ----------------
// gates : @0        (160 gates * 8 floats = 5120 B)
// iperm : @8192     (16*1024*4 = 64 KB)  forward CNOT-block gather tables
// invs  : @81920    (8192*4 = 32 KB)
// Xh    : @1 MB     (8192*1024*2 = 16 MB)   f16 cast of x, row-major (B,K)
// B_il  : @17 MB    (2048*1024*2 = 4 MB)    f16, rows 2j=Re U[j,:], 2j+1=Im U[j,:]
// Ucol  : scratch in d_out (4 MB needed, d_out is 32 MB; fully overwritten by gemm)
#define WS_GATES 0
#define WS_IPERM 8192
#define WS_INVS  81920
#define WS_XH    (1u << 20)
#define WS_BIL   (17u << 20)

// padded LDS slot: breaks power-of-2 stride bank conflicts (16-way -> <=4-way)
#define SLOT(i) ((i) + ((i) >> 4))

__device__ inline void gate2(const float* __restrict__ g, float2& p0, float2& p1) {
    float m00r = g[0], m00i = g[1], m01r = g[2], m01i = g[3];
    float m10r = g[4], m10i = g[5], m11r = g[6], m11i = g[7];
    float n0x = m00r*p0.x - m00i*p0.y + m01r*p1.x - m01i*p1.y;
    float n0y = m00r*p0.y + m00i*p0.x + m01r*p1.y + m01i*p1.x;
    float n1x = m10r*p0.x - m10i*p0.y + m11r*p1.x - m11i*p1.y;
    float n1y = m10r*p0.y + m10i*p0.x + m11r*p1.y + m11i*p1.x;
    p0 = make_float2(n0x, n0y);
    p1 = make_float2(n1x, n1y);
}

__global__ __launch_bounds__(1024)
void prep_kernel(const float* __restrict__ w, float* __restrict__ gates,
                 int* __restrict__ iperm) {
    int t = threadIdx.x;
    const float PI = 3.14159265358979323846f;
    if (t < QDEPTH * NW) {
        // Rot(phi,theta,omega) = RZ(omega) RY(theta) RZ(phi); angles = tanh(w)*pi
        float phi   = tanhf(w[t*3 + 0]) * PI;
        float theta = tanhf(w[t*3 + 1]) * PI;
        float omega = tanhf(w[t*3 + 2]) * PI;
        float ch = cosf(theta * 0.5f), sh = sinf(theta * 0.5f);
        float ap = (phi + omega) * 0.5f;
        float am = (phi - omega) * 0.5f;
        float* g = gates + t * 8;
        g[0] =  cosf(ap) * ch;  g[1] = -sinf(ap) * ch;   // m00
        g[2] = -cosf(am) * sh;  g[3] = -sinf(am) * sh;   // m01
        g[4] =  cosf(am) * sh;  g[5] = -sinf(am) * sh;   // m10
        g[6] =  cosf(ap) * ch;  g[7] =  sinf(ap) * ch;   // m11
    }
    // Forward CNOT-block gather (round-1 verified): state'[v] = state[G_l(v)]
    int v = t;
    for (int l = 0; l < QDEPTH; ++l) {
        int r = (l % (NW - 1)) + 1;
        int u = v;
        for (int wq = NW - 1; wq >= 0; --wq) {
            int bc = 9 - wq;
            int bt = 9 - ((wq + r) % NW);
            u ^= ((u >> bc) & 1) << bt;
        }
        iperm[l * DIM + v] = u;
    }
}

// Column builder (round-2 structure, slot-padded LDS + coalesced column writes).
// Block v simulates basis state e_v and writes column v of U contiguously:
// Ucol[v][2j] = Re U[j,v], Ucol[v][2j+1] = Im U[j,v].
__global__ __launch_bounds__(256)
void ubuild_kernel(const float* __restrict__ gates, const int* __restrict__ iperm,
                   _Float16* __restrict__ Ucol) {
    __shared__ float2 st[DIM + 64];
    const int v = blockIdx.x;
    const int t = threadIdx.x;

    #pragma unroll
    for (int k = 0; k < 4; ++k) {
        int i = t + k * 256;
        st[SLOT(i)] = make_float2(i == v ? 1.f : 0.f, 0.f);
    }
    __syncthreads();

    for (int l = 0; l < QDEPTH; ++l) {
        const float* gl = gates + l * NW * 8;
        #pragma unroll
        for (int pb = 4; pb >= 0; --pb) {
            const int b = 2 * pb;
            const float* gh = gl + (8 - b) * 8;     // gate on bit b+1 (wire 8-b)
            const float* gm = gl + (9 - b) * 8;     // gate on bit b   (wire 9-b)
            const int low = t & ((1 << b) - 1);
            const int i00 = ((t >> b) << (b + 2)) | low;
            const int i01 = i00 | (1 << b);
            const int i10 = i00 | (2 << b);
            const int i11 = i00 | (3 << b);
            float2 a00 = st[SLOT(i00)], a01 = st[SLOT(i01)];
            float2 a10 = st[SLOT(i10)], a11 = st[SLOT(i11)];
            gate2(gh, a00, a10);
            gate2(gh, a01, a11);
            gate2(gm, a00, a01);
            gate2(gm, a10, a11);
            st[SLOT(i00)] = a00; st[SLOT(i01)] = a01;
            st[SLOT(i10)] = a10; st[SLOT(i11)] = a11;
            __syncthreads();
        }
        const int* ip = iperm + l * DIM;
        int j0 = ip[t], j1 = ip[t + 256], j2 = ip[t + 512], j3 = ip[t + 768];
        float2 b0 = st[SLOT(j0)], b1 = st[SLOT(j1)];
        float2 b2 = st[SLOT(j2)], b3 = st[SLOT(j3)];
        __syncthreads();
        st[SLOT(t)]       = b0;
        st[SLOT(t + 256)] = b1;
        st[SLOT(t + 512)] = b2;
        st[SLOT(t + 768)] = b3;
        __syncthreads();
    }

    // coalesced column write: 4-byte f16 pairs, consecutive threads -> consecutive addrs
    _Float16* col = Ucol + (size_t)v * 2048;
    #pragma unroll
    for (int k = 0; k < 4; ++k) {
        int i = t + k * 256;
        float2 a = st[SLOT(i)];
        f16x2 p;
        p[0] = (_Float16)a.x;
        p[1] = (_Float16)a.y;
        *(f16x2*)(col + 2 * i) = p;
    }
}

// Bil[n][k] = Ucol[k][n], n<2048, k<1024. LDS-tiled 64x64 transpose.
__global__ __launch_bounds__(256)
void transpose_kernel(const _Float16* __restrict__ Ucol, _Float16* __restrict__ Bil) {
    __shared__ _Float16 tile[64][72];   // +8 f16 pad to spread column reads
    const int bx = blockIdx.x;          // n-tile: 0..31
    const int by = blockIdx.y;          // k-tile: 0..15
    const int t  = threadIdx.x;
    const int r  = t >> 3;              // 0..31
    const int c8 = (t & 7) * 8;         // 0..56

    #pragma unroll
    for (int kk = 0; kk < 64; kk += 32) {
        *(f16x8*)&tile[kk + r][c8] =
            *(const f16x8*)(Ucol + (size_t)(by * 64 + kk + r) * 2048 + bx * 64 + c8);
    }
    __syncthreads();
    #pragma unroll
    for (int nn = 0; nn < 64; nn += 32) {
        f16x8 o;
        #pragma unroll
        for (int j = 0; j < 8; ++j) o[j] = tile[c8 + j][nn + r];
        *(f16x8*)(Bil + (size_t)(bx * 64 + nn + r) * 1024 + by * 64 + c8) = o;
    }
}

// Per-row sumsq + f16 cast. One wave per batch row.
__global__ __launch_bounds__(64)
void normcast_kernel(const float* __restrict__ x, _Float16* __restrict__ Xh,
                     float* __restrict__ invs) {
    const int b = blockIdx.x;
    const int l = threadIdx.x;
    const float4* xr = (const float4*)(x + (size_t)b * DIM);
    float4 v[4];
    float ss = 0.f;
    #pragma unroll
    for (int c = 0; c < 4; ++c) {
        v[c] = xr[l + c * 64];
        ss += v[c].x*v[c].x + v[c].y*v[c].y + v[c].z*v[c].z + v[c].w*v[c].w;
    }
    #pragma unroll
    for (int o = 32; o >= 1; o >>= 1) ss += __shfl_down(ss, o, 64);
    ss = __shfl(ss, 0, 64);
    if (l == 0) invs[b] = 1024.0f / ss;
    f16x4* xo = (f16x4*)(Xh + (size_t)b * DIM);
    #pragma unroll
    for (int c = 0; c < 4; ++c) {
        f16x4 h;
        h[0] = (_Float16)v[c].x; h[1] = (_Float16)v[c].y;
        h[2] = (_Float16)v[c].z; h[3] = (_Float16)v[c].w;
        xo[l + c * 64] = h;
    }
}

// C[b,n] = sum_k Xh[b,k] * Bil[n,k];  out[b, n>>1] = clip(invs[b]*(c_even^2+c_odd^2), 0, 1)
// M=8192, N=2048, K=1024. 128x128 tile, BK=32, 4 waves (2x2), 4x4 16x16x32 frags/wave.
#define BM 128
#define BN 128
#define BK 32

__global__ __launch_bounds__(256)
void gemm_kernel(const _Float16* __restrict__ A, const _Float16* __restrict__ B,
                 const float* __restrict__ invs, float* __restrict__ out) {
    __shared__ _Float16 As[BM * BK];   // 8 KB, row-major [128][32]
    __shared__ _Float16 Bs[BN * BK];   // 8 KB
    const int t    = threadIdx.x;
    const int lane = t & 63;
    const int wid  = t >> 6;
    const int wm = wid >> 1, wn = wid & 1;
    const int m0 = blockIdx.y * BM;
    const int n0 = blockIdx.x * BN;

    const int srow   = t >> 2;
    const int schunk = (t & 3) * 8;
    const _Float16* Ag = A + (size_t)(m0 + srow) * 1024 + schunk;
    const _Float16* Bg = B + (size_t)(n0 + srow) * 1024 + schunk;

    f32x4 acc[4][4];
    const f32x4 zero = {0.f, 0.f, 0.f, 0.f};
    #pragma unroll
    for (int i = 0; i < 4; ++i)
        #pragma unroll
        for (int j = 0; j < 4; ++j) acc[i][j] = zero;

    const int fr = lane & 15;
    const int fk = (lane >> 4) * 8;

    for (int kt = 0; kt < 1024; kt += BK) {
        __syncthreads();
        __builtin_amdgcn_global_load_lds(
            (const __attribute__((address_space(1))) void*)(Ag + kt),
            (__attribute__((address_space(3))) void*)(As + t * 8), 16, 0, 0);
        __builtin_amdgcn_global_load_lds(
            (const __attribute__((address_space(1))) void*)(Ag + kt + 64 * 1024),
            (__attribute__((address_space(3))) void*)(As + 2048 + t * 8), 16, 0, 0);
        __builtin_amdgcn_global_load_lds(
            (const __attribute__((address_space(1))) void*)(Bg + kt),
            (__attribute__((address_space(3))) void*)(Bs + t * 8), 16, 0, 0);
        __builtin_amdgcn_global_load_lds(
            (const __attribute__((address_space(1))) void*)(Bg + kt + 64 * 1024),
            (__attribute__((address_space(3))) void*)(Bs + 2048 + t * 8), 16, 0, 0);
        __syncthreads();

        f16x8 af[4], bf[4];
        #pragma unroll
        for (int mf = 0; mf < 4; ++mf)
            af[mf] = *(const f16x8*)(As + (wm * 64 + mf * 16 + fr) * BK + fk);
        #pragma unroll
        for (int nf = 0; nf < 4; ++nf)
            bf[nf] = *(const f16x8*)(Bs + (wn * 64 + nf * 16 + fr) * BK + fk);
        #pragma unroll
        for (int mf = 0; mf < 4; ++mf)
            #pragma unroll
            for (int nf = 0; nf < 4; ++nf)
                acc[mf][nf] = __builtin_amdgcn_mfma_f32_16x16x32_f16(
                    af[mf], bf[nf], acc[mf][nf], 0, 0, 0);
    }

    const int colf = lane & 15;
    const int rowf = (lane >> 4) * 4;
    #pragma unroll
    for (int mf = 0; mf < 4; ++mf) {
        #pragma unroll
        for (int nf = 0; nf < 4; ++nf) {
            const int n = n0 + wn * 64 + nf * 16 + colf;
            #pragma unroll
            for (int r = 0; r < 4; ++r) {
                const int row = m0 + wm * 64 + mf * 16 + rowf + r;
                float vv = acc[mf][nf][r];
                float sq = vv * vv;
                float other = __shfl_xor(sq, 1, 64);
                if (!(lane & 1)) {
                    float p = fminf((sq + other) * invs[row], 1.0f);
                    out[(size_t)row * DIM + (n >> 1)] = p;
                }
            }
        }
    }
}

extern "C" void kernel_launch(void* const* d_in, const int* in_sizes, int n_in,
                              void* d_out, int out_size, void* d_ws, size_t ws_size,
                              hipStream_t stream) {
    const float* x = (const float*)d_in[0];     // (8192,1,32,32) fp32
    const float* w = (const float*)d_in[1];     // (16,10,3) fp32
    float* out = (float*)d_out;                 // (8192,1,32,32) fp32

    char* ws = (char*)d_ws;
    float*     gates = (float*)(ws + WS_GATES);
    int*       iperm = (int*)(ws + WS_IPERM);
    float*     invs  = (float*)(ws + WS_INVS);
    _Float16*  Xh    = (_Float16*)(ws + WS_XH);
    _Float16*  Bil   = (_Float16*)(ws + WS_BIL);
    // Ucol scratch lives in d_out (4 MB of its 32 MB); consumed by transpose
    // before gemm overwrites every element of d_out.
    _Float16*  Ucol  = (_Float16*)d_out;

    prep_kernel<<<1, 1024, 0, stream>>>(w, gates, iperm);
    normcast_kernel<<<8192, 64, 0, stream>>>(x, Xh, invs);
    ubuild_kernel<<<1024, 256, 0, stream>>>(gates, iperm, Ucol);
    transpose_kernel<<<dim3(32, 16), 256, 0, stream>>>(Ucol, Bil);
    gemm_kernel<<<dim3(16, 64), 256, 0, stream>>>(Xh, Bil, invs, out);
}